// Round 10
// baseline (141.510 us; speedup 1.0000x reference)
//
#include <hip/hip_runtime.h>
#include <hip/hip_bf16.h>
#include <math.h>

#define N_NODES 1024
#define T_DIM 8

typedef __bf16 bf16x8 __attribute__((ext_vector_type(8)));
typedef float  f32x4  __attribute__((ext_vector_type(4)));

__device__ __forceinline__ float readlane_f(float v, int l) {
    return __uint_as_float(__builtin_amdgcn_readlane(__float_as_uint(v), l));
}

// ---- Kernel A2: permute adj into A-fragment-ordered 4KB tiles ---------------
// adjT[((t*64+itile)*16+jt)*1024 + lane*16 + kc*8 + m] =
//   adj[t][itile*16 + (lane&15)][jt*64 + (lane>>4)*8 + kc*32 + m]
// Kernel B then reads its entire adj tile as 4 contiguous dwordx4 per lane.
__global__ __launch_bounds__(256) void adj_tile_kernel(
    const float* __restrict__ adj, float* __restrict__ adjT)
{
    const int t     = blockIdx.y;        // 0..7
    const int itile = blockIdx.x;        // 0..63
    const int tid   = threadIdx.x;
    const int lane  = tid & 63;
    const int w     = tid >> 6;          // 0..3

    const float* src = adj + (size_t)t * N_NODES * N_NODES
                           + (size_t)(itile * 16 + (lane & 15)) * N_NODES
                           + (lane >> 4) * 8;
    float* dst = adjT + (size_t)(t * 64 + itile) * 16 * 1024 + lane * 16;

#pragma unroll
    for (int jj = 0; jj < 4; ++jj) {
        const int jt = w + jj * 4;
        f32x4 v0 = *(const f32x4*)(src + jt * 64);
        f32x4 v1 = *(const f32x4*)(src + jt * 64 + 4);
        f32x4 v2 = *(const f32x4*)(src + jt * 64 + 32);
        f32x4 v3 = *(const f32x4*)(src + jt * 64 + 36);
        f32x4* d = (f32x4*)(dst + (size_t)jt * 1024);
        d[0] = v0; d[1] = v1; d[2] = v2; d[3] = v3;
    }
}

// ---- Kernel A: h = inp@W ; s1,s2 ; hF = (h*mask_j) in B-frag-ordered tiles --
// hF tile (bt,jt) = 8 chunks of 1KB; chunk c=kc*4+nc, lane l, m 0..7 holds
// h[o = nc*16 + (l&15)][j = jt*64 + (l>>4)*8 + kc*32 + m] * mask_j.
// Kernel B reads 8 contiguous dwordx4 per tile. mask_j folded here (hF only
// feeds PV; softmax denominator is unmasked per the reference).
__global__ __launch_bounds__(256) void gat_h_kernel(
    const float* __restrict__ inp, const float* __restrict__ W,
    const float* __restrict__ a, const float* __restrict__ att_mask,
    __bf16* __restrict__ hF, float* __restrict__ s1w, float* __restrict__ s2w)
{
    __shared__ float Wl[64 * 64];
    __shared__ float xl[64 * 64];
    __shared__ __bf16 htl[64 * 72];   // [o][j], stride 72 (16B-aligned rows)

    const int tid  = threadIdx.x;
    const int blk  = blockIdx.x;
    const int bt   = blk >> 4;
    const int b    = bt >> 3;
    const int t    = bt & 7;
    const int nt   = blk & 15;        // j-tile
    const int n0   = nt * 64;
    const int lane = tid & 63;        // = o in compute phase
    const int wave = tid >> 6;

    const float4* W4  = (const float4*)W;
    float4*       Wl4 = (float4*)Wl;
    const float4* x4  = (const float4*)(inp + (size_t)(bt * N_NODES + n0) * 64);
    float4*       xl4 = (float4*)xl;
#pragma unroll
    for (int k = 0; k < 4; ++k) {
        Wl4[tid + k * 256] = W4[tid + k * 256];
        xl4[tid + k * 256] = x4[tid + k * 256];
    }
    const float a1 = a[lane];
    const float a2 = a[64 + lane];
    __syncthreads();

#pragma unroll 1
    for (int rg = 0; rg < 16; rg += 4) {
        float xr[4], acc[4];
#pragma unroll
        for (int q = 0; q < 4; ++q) {
            xr[q]  = xl[(wave * 16 + rg + q) * 64 + lane];
            acc[q] = 0.f;
        }
#pragma unroll
        for (int f = 0; f < 64; ++f) {
            float w = Wl[f * 64 + lane];
#pragma unroll
            for (int q = 0; q < 4; ++q)
                acc[q] = fmaf(readlane_f(xr[q], f), w, acc[q]);
        }
#pragma unroll
        for (int q = 0; q < 4; ++q) {
            const int r = wave * 16 + rg + q;   // local j
            float v1 = acc[q] * a1, v2 = acc[q] * a2;
#pragma unroll
            for (int off = 32; off; off >>= 1) {
                v1 += __shfl_xor(v1, off, 64);
                v2 += __shfl_xor(v2, off, 64);
            }
            if (lane == 0) {
                s1w[bt * N_NODES + n0 + r] = v1;
                s2w[bt * N_NODES + n0 + r] = v2;
            }
            const float mjr = att_mask[((size_t)b * N_NODES + n0 + r) * T_DIM + t];
            htl[lane * 72 + r] = (__bf16)(acc[q] * mjr);   // [o][j]
        }
    }
    __syncthreads();

    // write B-frag-ordered chunks: thread t -> lane l=t&63, chunks {w, w+4}
    {
        const int l  = tid & 63;
        const int w  = tid >> 6;
        __bf16* tbase = hF + (size_t)(bt * 16 + nt) * 4096;
#pragma unroll
        for (int cc = 0; cc < 2; ++cc) {
            const int c  = w + cc * 4;       // chunk = kc*4 + nc
            const int nc = c & 3;
            const int kc = c >> 2;
            bf16x8 v = *(const bf16x8*)&htl[(nc * 16 + (l & 15)) * 72
                                            + (l >> 4) * 8 + kc * 32];
            *(bf16x8*)(tbase + (c * 64 + l) * 8) = v;
        }
    }
}

// ---- Kernel B: LDS-free flash GAT, every VMEM instruction lane-contiguous ---
// grid (64 i-tiles, 32 bt) x 64 thr. P computed directly in A-frag registers
// (r7 scheme); adj from adjT tiles (4 contiguous dwordx4/iter); h from hF
// tiles (8 contiguous dwordx4/iter); s2 quad-segment loads. i-only phase
// stagger keeps b-siblings aligned (L3 reuse) while de-correlating i-blocks.
// No LDS, no barriers, no in-loop shuffles; 1-tile register prefetch.
__global__ __launch_bounds__(64) void gat_attn_kernel(
    const float* __restrict__ adjT, const float* __restrict__ att_mask,
    const __bf16* __restrict__ hF, const float* __restrict__ s1w,
    const float* __restrict__ s2w, float* __restrict__ out)
{
    const int bt    = blockIdx.y;
    const int b     = bt >> 3;
    const int t     = bt & 7;
    const int itile = blockIdx.x;
    const int irow0 = itile * 16;
    const int lane  = threadIdx.x;
    const int l15   = lane & 15;
    const int quad  = lane >> 4;
    const int phase = itile & 15;

    f32x4 acc[4];
#pragma unroll
    for (int nc = 0; nc < 4; ++nc) acc[nc] = (f32x4){0.f, 0.f, 0.f, 0.f};
    float lsum = 0.f;
    const float s1r = s1w[bt * N_NODES + irow0 + l15];

    const float*  atb = adjT + (size_t)(t * 64 + itile) * 16 * 1024 + lane * 16;
    const __bf16* htb = hF + (size_t)bt * 16 * 4096 + lane * 8;
    const float*  s2p = s2w + bt * N_NODES + quad * 8;

    // ---- preload tile `phase` ----
    f32x4  adjc[4];
    f32x4  s2c[4];
    bf16x8 hc[8];
    {
        const int jt = phase;
        const float* ap = atb + (size_t)jt * 1024;
#pragma unroll
        for (int k = 0; k < 4; ++k) adjc[k] = *(const f32x4*)(ap + k * 4);
#pragma unroll
        for (int k = 0; k < 2; ++k) {
            s2c[k]     = *(const f32x4*)(s2p + jt * 64 + k * 4);
            s2c[2 + k] = *(const f32x4*)(s2p + jt * 64 + 32 + k * 4);
        }
        const __bf16* hp = htb + (size_t)jt * 4096;
#pragma unroll
        for (int c = 0; c < 8; ++c) hc[c] = *(const bf16x8*)(hp + c * 512);
    }

#pragma unroll 2
    for (int it = 0; it < 16; ++it) {
        const int jn = (it + 1 + phase) & 15;   // next tile (ring; tail unused)

        // ---- prefetch next tile (all lane-contiguous) ----
        f32x4  adjn[4], s2n[4];
        bf16x8 hn[8];
        {
            const float* ap = atb + (size_t)jn * 1024;
#pragma unroll
            for (int k = 0; k < 4; ++k) adjn[k] = *(const f32x4*)(ap + k * 4);
#pragma unroll
            for (int k = 0; k < 2; ++k) {
                s2n[k]     = *(const f32x4*)(s2p + jn * 64 + k * 4);
                s2n[2 + k] = *(const f32x4*)(s2p + jn * 64 + 32 + k * 4);
            }
            const __bf16* hp = htb + (size_t)jn * 4096;
#pragma unroll
            for (int c = 0; c < 8; ++c) hn[c] = *(const bf16x8*)(hp + c * 512);
        }

        // ---- scores in A-frag register order; leaky bounds e*adj in [-6,~16]
        // so exp never overflows -> no max pass needed ----
        const float* ac = (const float*)adjc;   // idx = kc*8 + m
        const float* sc = (const float*)s2c;
        bf16x8 af[2];
#pragma unroll
        for (int kc = 0; kc < 2; ++kc)
#pragma unroll
            for (int m = 0; m < 8; ++m) {
                float av = ac[kc * 8 + m];
                float e  = s1r + sc[kc * 8 + m];
                e = fmaxf(e, 0.2f * e);
                float p = (av > 0.f) ? __expf(e * av) : 0.f;
                lsum += p;
                af[kc][m] = (__bf16)p;
            }

        // ---- 8 MFMAs ----
#pragma unroll
        for (int nc = 0; nc < 4; ++nc)
            acc[nc] = __builtin_amdgcn_mfma_f32_16x16x32_bf16(af[0], hc[nc], acc[nc], 0, 0, 0);
#pragma unroll
        for (int nc = 0; nc < 4; ++nc)
            acc[nc] = __builtin_amdgcn_mfma_f32_16x16x32_bf16(af[1], hc[4 + nc], acc[nc], 0, 0, 0);

        // ---- rotate prefetch buffers (unroll-2 renames copies away) ----
#pragma unroll
        for (int k = 0; k < 4; ++k) { adjc[k] = adjn[k]; s2c[k] = s2n[k]; }
#pragma unroll
        for (int c = 0; c < 8; ++c) hc[c] = hn[c];
    }

    // ---- epilogue: quad-reduce lsum, mi/ls scale + ELU + store ----
    lsum += __shfl_xor(lsum, 16, 64);
    lsum += __shfl_xor(lsum, 32, 64);   // row total in all 4 quad-lanes

#pragma unroll
    for (int reg = 0; reg < 4; ++reg) {
        const int i = irow0 + quad * 4 + reg;           // C/D row = quad*4+reg
        float ls = __shfl(lsum, quad * 4 + reg, 64);    // row i's denominator
        float mi = att_mask[((size_t)b * N_NODES + i) * T_DIM + t];
        float scale = mi / ls;
#pragma unroll
        for (int nc = 0; nc < 4; ++nc) {
            float v = acc[nc][reg] * scale;
            v = (v > 0.f) ? v : (__expf(v) - 1.f);
            out[((size_t)bt * N_NODES + i) * 64 + nc * 16 + l15] = v;
        }
    }
}

extern "C" void kernel_launch(void* const* d_in, const int* in_sizes, int n_in,
                              void* d_out, int out_size, void* d_ws, size_t ws_size,
                              hipStream_t stream) {
    (void)in_sizes; (void)n_in; (void)out_size; (void)ws_size;
    const float* adj      = (const float*)d_in[0];   // (T,N,N)
    const float* inp      = (const float*)d_in[1];   // (B,T,N,FI)
    const float* att_mask = (const float*)d_in[2];   // (B,N,T)
    const float* W        = (const float*)d_in[3];   // (FI,FO)
    const float* a        = (const float*)d_in[4];   // (2*FO,1)
    float* out = (float*)d_out;

    // ws layout: adjT 32MB | hF 4MB | s1 128KB | s2 128KB  (~36.3 MB total)
    float*  adjT = (float*)d_ws;
    __bf16* hF   = (__bf16*)((char*)d_ws + (size_t)32 * 1024 * 1024);
    float*  s1w  = (float*)((char*)d_ws + (size_t)36 * 1024 * 1024);
    float*  s2w  = s1w + 32 * N_NODES;

    dim3 gA2(64, 8);
    adj_tile_kernel<<<gA2, 256, 0, stream>>>(adj, adjT);
    gat_h_kernel<<<512, 256, 0, stream>>>(inp, W, a, att_mask, hF, s1w, s2w);
    dim3 grid(64, 32);
    gat_attn_kernel<<<grid, 64, 0, stream>>>(adjT, att_mask, hF, s1w, s2w, out);
}

// Round 11
// 141.386 us; speedup vs baseline: 1.0009x; 1.0009x over previous
//
#include <hip/hip_runtime.h>
#include <hip/hip_bf16.h>
#include <math.h>

#define N_NODES 1024
#define T_DIM 8

typedef __bf16 bf16x8 __attribute__((ext_vector_type(8)));
typedef float  f32x4  __attribute__((ext_vector_type(4)));

__device__ __forceinline__ float readlane_f(float v, int l) {
    return __uint_as_float(__builtin_amdgcn_readlane(__float_as_uint(v), l));
}

// ---- Kernel A (fused): h = inp@W ; s1,s2 ; hF tiles ; adjT permute slice ----
// Phase 1: h = inp@W, s1/s2, write hF = (h*mask_j) in B-frag-ordered 8KB tiles.
// Phase 2: this block also permutes its 64KB slice of adj into A-frag-ordered
// adjT tiles (t = bt&7, itile = b*16+nt — each (t,itile) covered exactly once).
// Fusing overlaps the permute's memory stream with compute instead of paying a
// serialized ~13us dispatch (graph keeps stream order between kernels).
__global__ __launch_bounds__(256) void gat_h_kernel(
    const float* __restrict__ inp, const float* __restrict__ W,
    const float* __restrict__ a, const float* __restrict__ att_mask,
    const float* __restrict__ adj, float* __restrict__ adjT,
    __bf16* __restrict__ hF, float* __restrict__ s1w, float* __restrict__ s2w)
{
    __shared__ float Wl[64 * 64];
    __shared__ float xl[64 * 64];
    __shared__ __bf16 htl[64 * 72];   // [o][j], stride 72 (16B-aligned rows)

    const int tid  = threadIdx.x;
    const int blk  = blockIdx.x;
    const int bt   = blk >> 4;
    const int b    = bt >> 3;
    const int t    = bt & 7;
    const int nt   = blk & 15;        // j-tile
    const int n0   = nt * 64;
    const int lane = tid & 63;        // = o in compute phase
    const int wave = tid >> 6;

    const float4* W4  = (const float4*)W;
    float4*       Wl4 = (float4*)Wl;
    const float4* x4  = (const float4*)(inp + (size_t)(bt * N_NODES + n0) * 64);
    float4*       xl4 = (float4*)xl;
#pragma unroll
    for (int k = 0; k < 4; ++k) {
        Wl4[tid + k * 256] = W4[tid + k * 256];
        xl4[tid + k * 256] = x4[tid + k * 256];
    }
    const float a1 = a[lane];
    const float a2 = a[64 + lane];
    __syncthreads();

#pragma unroll 1
    for (int rg = 0; rg < 16; rg += 4) {
        float xr[4], acc[4];
#pragma unroll
        for (int q = 0; q < 4; ++q) {
            xr[q]  = xl[(wave * 16 + rg + q) * 64 + lane];
            acc[q] = 0.f;
        }
#pragma unroll
        for (int f = 0; f < 64; ++f) {
            float w = Wl[f * 64 + lane];
#pragma unroll
            for (int q = 0; q < 4; ++q)
                acc[q] = fmaf(readlane_f(xr[q], f), w, acc[q]);
        }
#pragma unroll
        for (int q = 0; q < 4; ++q) {
            const int r = wave * 16 + rg + q;   // local j
            float v1 = acc[q] * a1, v2 = acc[q] * a2;
#pragma unroll
            for (int off = 32; off; off >>= 1) {
                v1 += __shfl_xor(v1, off, 64);
                v2 += __shfl_xor(v2, off, 64);
            }
            if (lane == 0) {
                s1w[bt * N_NODES + n0 + r] = v1;
                s2w[bt * N_NODES + n0 + r] = v2;
            }
            const float mjr = att_mask[((size_t)b * N_NODES + n0 + r) * T_DIM + t];
            htl[lane * 72 + r] = (__bf16)(acc[q] * mjr);   // [o][j]
        }
    }
    __syncthreads();

    // write B-frag-ordered chunks: thread -> lane l=tid&63, chunks {w, w+4}
    {
        const int l  = tid & 63;
        const int w  = tid >> 6;
        __bf16* tbase = hF + (size_t)(bt * 16 + nt) * 4096;
#pragma unroll
        for (int cc = 0; cc < 2; ++cc) {
            const int c  = w + cc * 4;       // chunk = kc*4 + nc
            const int nc = c & 3;
            const int kc = c >> 2;
            bf16x8 v = *(const bf16x8*)&htl[(nc * 16 + (l & 15)) * 72
                                            + (l >> 4) * 8 + kc * 32];
            *(bf16x8*)(tbase + (c * 64 + l) * 8) = v;
        }
    }

    // ---- Phase 2: permute this block's adj slice into adjT ----
    // adjT[((t*64+itile)*16+jt)*1024 + lane*16 + kc*8 + m] =
    //   adj[t][itile*16 + (lane&15)][jt*64 + (lane>>4)*8 + kc*32 + m]
    {
        const int itile = b * 16 + nt;     // 0..63, each (t,itile) once
        const float* src = adj + (size_t)t * N_NODES * N_NODES
                               + (size_t)(itile * 16 + (lane & 15)) * N_NODES
                               + (lane >> 4) * 8;
        float* dst = adjT + (size_t)(t * 64 + itile) * 16 * 1024 + lane * 16;
#pragma unroll
        for (int jj = 0; jj < 4; ++jj) {
            const int jt = wave + jj * 4;
            f32x4 v0 = *(const f32x4*)(src + jt * 64);
            f32x4 v1 = *(const f32x4*)(src + jt * 64 + 4);
            f32x4 v2 = *(const f32x4*)(src + jt * 64 + 32);
            f32x4 v3 = *(const f32x4*)(src + jt * 64 + 36);
            f32x4* d = (f32x4*)(dst + (size_t)jt * 1024);
            d[0] = v0; d[1] = v1; d[2] = v2; d[3] = v3;
        }
    }
}

// ---- Kernel B: LDS-free flash GAT, every VMEM instruction lane-contiguous ---
// (unchanged from r10 — best measured attn) grid (64 i-tiles, 32 bt) x 64 thr.
// P computed directly in A-frag registers; adj from adjT tiles (4 contiguous
// dwordx4/iter); h from hF tiles (8 contiguous dwordx4/iter). i-only phase
// stagger keeps b-siblings aligned (L3 reuse) while de-correlating i-blocks.
// No LDS, no barriers, no in-loop shuffles; 1-tile register prefetch.
__global__ __launch_bounds__(64) void gat_attn_kernel(
    const float* __restrict__ adjT, const float* __restrict__ att_mask,
    const __bf16* __restrict__ hF, const float* __restrict__ s1w,
    const float* __restrict__ s2w, float* __restrict__ out)
{
    const int bt    = blockIdx.y;
    const int b     = bt >> 3;
    const int t     = bt & 7;
    const int itile = blockIdx.x;
    const int irow0 = itile * 16;
    const int lane  = threadIdx.x;
    const int l15   = lane & 15;
    const int quad  = lane >> 4;
    const int phase = itile & 15;

    f32x4 acc[4];
#pragma unroll
    for (int nc = 0; nc < 4; ++nc) acc[nc] = (f32x4){0.f, 0.f, 0.f, 0.f};
    float lsum = 0.f;
    const float s1r = s1w[bt * N_NODES + irow0 + l15];

    const float*  atb = adjT + (size_t)(t * 64 + itile) * 16 * 1024 + lane * 16;
    const __bf16* htb = hF + (size_t)bt * 16 * 4096 + lane * 8;
    const float*  s2p = s2w + bt * N_NODES + quad * 8;

    // ---- preload tile `phase` ----
    f32x4  adjc[4];
    f32x4  s2c[4];
    bf16x8 hc[8];
    {
        const int jt = phase;
        const float* ap = atb + (size_t)jt * 1024;
#pragma unroll
        for (int k = 0; k < 4; ++k) adjc[k] = *(const f32x4*)(ap + k * 4);
#pragma unroll
        for (int k = 0; k < 2; ++k) {
            s2c[k]     = *(const f32x4*)(s2p + jt * 64 + k * 4);
            s2c[2 + k] = *(const f32x4*)(s2p + jt * 64 + 32 + k * 4);
        }
        const __bf16* hp = htb + (size_t)jt * 4096;
#pragma unroll
        for (int c = 0; c < 8; ++c) hc[c] = *(const bf16x8*)(hp + c * 512);
    }

#pragma unroll 2
    for (int it = 0; it < 16; ++it) {
        const int jn = (it + 1 + phase) & 15;   // next tile (ring; tail unused)

        // ---- prefetch next tile (all lane-contiguous) ----
        f32x4  adjn[4], s2n[4];
        bf16x8 hn[8];
        {
            const float* ap = atb + (size_t)jn * 1024;
#pragma unroll
            for (int k = 0; k < 4; ++k) adjn[k] = *(const f32x4*)(ap + k * 4);
#pragma unroll
            for (int k = 0; k < 2; ++k) {
                s2n[k]     = *(const f32x4*)(s2p + jn * 64 + k * 4);
                s2n[2 + k] = *(const f32x4*)(s2p + jn * 64 + 32 + k * 4);
            }
            const __bf16* hp = htb + (size_t)jn * 4096;
#pragma unroll
            for (int c = 0; c < 8; ++c) hn[c] = *(const bf16x8*)(hp + c * 512);
        }

        // ---- scores in A-frag register order; leaky bounds e*adj in [-6,~16]
        // so exp never overflows -> no max pass needed ----
        const float* ac = (const float*)adjc;   // idx = kc*8 + m
        const float* sc = (const float*)s2c;
        bf16x8 af[2];
#pragma unroll
        for (int kc = 0; kc < 2; ++kc)
#pragma unroll
            for (int m = 0; m < 8; ++m) {
                float av = ac[kc * 8 + m];
                float e  = s1r + sc[kc * 8 + m];
                e = fmaxf(e, 0.2f * e);
                float p = (av > 0.f) ? __expf(e * av) : 0.f;
                lsum += p;
                af[kc][m] = (__bf16)p;
            }

        // ---- 8 MFMAs ----
#pragma unroll
        for (int nc = 0; nc < 4; ++nc)
            acc[nc] = __builtin_amdgcn_mfma_f32_16x16x32_bf16(af[0], hc[nc], acc[nc], 0, 0, 0);
#pragma unroll
        for (int nc = 0; nc < 4; ++nc)
            acc[nc] = __builtin_amdgcn_mfma_f32_16x16x32_bf16(af[1], hc[4 + nc], acc[nc], 0, 0, 0);

        // ---- rotate prefetch buffers (unroll-2 renames copies away) ----
#pragma unroll
        for (int k = 0; k < 4; ++k) { adjc[k] = adjn[k]; s2c[k] = s2n[k]; }
#pragma unroll
        for (int c = 0; c < 8; ++c) hc[c] = hn[c];
    }

    // ---- epilogue: quad-reduce lsum, mi/ls scale + ELU + store ----
    lsum += __shfl_xor(lsum, 16, 64);
    lsum += __shfl_xor(lsum, 32, 64);   // row total in all 4 quad-lanes

#pragma unroll
    for (int reg = 0; reg < 4; ++reg) {
        const int i = irow0 + quad * 4 + reg;           // C/D row = quad*4+reg
        float ls = __shfl(lsum, quad * 4 + reg, 64);    // row i's denominator
        float mi = att_mask[((size_t)b * N_NODES + i) * T_DIM + t];
        float scale = mi / ls;
#pragma unroll
        for (int nc = 0; nc < 4; ++nc) {
            float v = acc[nc][reg] * scale;
            v = (v > 0.f) ? v : (__expf(v) - 1.f);
            out[((size_t)bt * N_NODES + i) * 64 + nc * 16 + l15] = v;
        }
    }
}

extern "C" void kernel_launch(void* const* d_in, const int* in_sizes, int n_in,
                              void* d_out, int out_size, void* d_ws, size_t ws_size,
                              hipStream_t stream) {
    (void)in_sizes; (void)n_in; (void)out_size; (void)ws_size;
    const float* adj      = (const float*)d_in[0];   // (T,N,N)
    const float* inp      = (const float*)d_in[1];   // (B,T,N,FI)
    const float* att_mask = (const float*)d_in[2];   // (B,N,T)
    const float* W        = (const float*)d_in[3];   // (FI,FO)
    const float* a        = (const float*)d_in[4];   // (2*FO,1)
    float* out = (float*)d_out;

    // ws layout: adjT 32MB | hF 4MB | s1 128KB | s2 128KB  (~36.3 MB total)
    float*  adjT = (float*)d_ws;
    __bf16* hF   = (__bf16*)((char*)d_ws + (size_t)32 * 1024 * 1024);
    float*  s1w  = (float*)((char*)d_ws + (size_t)36 * 1024 * 1024);
    float*  s2w  = s1w + 32 * N_NODES;

    gat_h_kernel<<<512, 256, 0, stream>>>(inp, W, a, att_mask, adj, adjT, hF, s1w, s2w);
    dim3 grid(64, 32);
    gat_attn_kernel<<<grid, 64, 0, stream>>>(adjT, att_mask, hF, s1w, s2w, out);
}